// Round 1
// baseline (298.046 us; speedup 1.0000x reference)
//
#include <hip/hip_runtime.h>
#include <hip/hip_bf16.h>

// NRI edge-MLP encoder: out[b,e,:] = relu(concat(x[b,send(e)], x[b,recv(e)]) @ W1^T + b1) @ W2^T + b2
// B=8, N=256, E=65280, n_in=64, n_hid=128, n_out=64.
// edge e: recv = e/255, k = e%255, send = k + (k >= recv)   [np.where row-major order]

using frag_t = __attribute__((ext_vector_type(8))) short;   // 8 bf16 = 4 VGPRs
using f32x4  = __attribute__((ext_vector_type(4))) float;

#define X_ELEMS  (8 * 256 * 64)   // 131072
#define W1_ELEMS (128 * 128)      // 16384
#define W2_ELEMS (64 * 128)       // 8192
#define W1_OFF   X_ELEMS          // 131072  (byte off 262144, 16B aligned)
#define W2_OFF   (X_ELEMS + W1_ELEMS)  // 147456 (byte off 294912, 16B aligned)

__device__ inline unsigned short f2bf(float f) {
    union { float f; unsigned u; } v; v.f = f;
    unsigned r = v.u + 0x7fffu + ((v.u >> 16) & 1u);   // RTNE
    return (unsigned short)(r >> 16);
}

__global__ __launch_bounds__(256) void cvt_bf16(const float* __restrict__ x,
                                                const float* __restrict__ W1,
                                                const float* __restrict__ W2,
                                                unsigned short* __restrict__ ws) {
    int i = blockIdx.x * 256 + threadIdx.x;
    if (i < X_ELEMS)  ws[i]          = f2bf(x[i]);
    if (i < W1_ELEMS) ws[W1_OFF + i] = f2bf(W1[i]);
    if (i < W2_ELEMS) ws[W2_OFF + i] = f2bf(W2[i]);
}

__global__ __launch_bounds__(256, 2) void nri_mlp(const unsigned short* __restrict__ ws,
                                                  const float* __restrict__ b1,
                                                  const float* __restrict__ b2,
                                                  float* __restrict__ out) {
    const unsigned short* xbf  = ws;
    const unsigned short* W1bf = ws + W1_OFF;
    const unsigned short* W2bf = ws + W2_OFF;

    // H: 128 rows x 128 hid, bf16, pad +8 -> row stride 136 elem (272 B = 68 words:
    // lane m reads row m -> bank offset 4*m % 32 -> 2-way conflict only (free).
    __shared__ unsigned short Hs[128 * 136];

    const int tid  = threadIdx.x;
    const int wave = tid >> 6;
    const int lane = tid & 63;
    const int quad = lane >> 4;
    const int n16  = lane & 15;

    const int bx = blockIdx.x;
    const int b  = bx / 510;
    const int eb = (bx - b * 510) * 128;   // 128 edges per block

    const unsigned short* xb = xbf + b * (256 * 64);

    // Per-lane gather base pointers for this wave's two 16-row tiles.
    // A-operand layout: lane holds A[m = lane&15][k = quad*8 + j], j=0..7.
    const unsigned short* pa[2][2];   // [tile][0=send half, 1=recv half]
    #pragma unroll
    for (int t = 0; t < 2; ++t) {
        int r    = wave * 32 + t * 16 + n16;
        int e    = eb + r;
        int recv = e / 255;
        int kk   = e - recv * 255;
        int send = kk + (kk >= recv ? 1 : 0);
        pa[t][0] = xb + send * 64;
        pa[t][1] = xb + recv * 64;
    }

    // ---------------- Layer 1: [128 x 128] = edges[128 x 128] @ W1^T ----------------
    f32x4 acc[2][8];
    #pragma unroll
    for (int t = 0; t < 2; ++t)
        #pragma unroll
        for (int c = 0; c < 8; ++c)
            acc[t][c] = (f32x4){0.f, 0.f, 0.f, 0.f};

    #pragma unroll
    for (int ks = 0; ks < 4; ++ks) {          // K = 128 = 4 x 32
        frag_t a[2];
        #pragma unroll
        for (int t = 0; t < 2; ++t) {
            const unsigned short* p = pa[t][ks >> 1] + (ks & 1) * 32 + quad * 8;
            a[t] = *(const frag_t*)p;          // 16B gather load from x (L1/L2-hot)
        }
        #pragma unroll
        for (int c = 0; c < 8; ++c) {
            // B-operand: lane n holds B[k][n] = W1[16c+n][k0 + quad*8 + j] (row-major W1)
            frag_t bf = *(const frag_t*)(W1bf + (c * 16 + n16) * 128 + ks * 32 + quad * 8);
            #pragma unroll
            for (int t = 0; t < 2; ++t)
                acc[t][c] = __builtin_amdgcn_mfma_f32_16x16x32_bf16(a[t], bf, acc[t][c], 0, 0, 0);
        }
    }

    // bias + ReLU + write H to LDS (C/D layout: col = lane&15, row = quad*4 + reg)
    #pragma unroll
    for (int c = 0; c < 8; ++c) {
        float bv = b1[c * 16 + n16];
        #pragma unroll
        for (int t = 0; t < 2; ++t) {
            #pragma unroll
            for (int r = 0; r < 4; ++r) {
                float v = acc[t][c][r] + bv;
                v = v > 0.f ? v : 0.f;
                int row = wave * 32 + t * 16 + quad * 4 + r;
                Hs[row * 136 + c * 16 + n16] = f2bf(v);
            }
        }
    }
    __syncthreads();   // wave-private rows, kept for safety in round 1

    // ---------------- Layer 2: [128 x 64] = H[128 x 128] @ W2^T ----------------
    f32x4 acc2[2][4];
    #pragma unroll
    for (int t = 0; t < 2; ++t)
        #pragma unroll
        for (int c = 0; c < 4; ++c)
            acc2[t][c] = (f32x4){0.f, 0.f, 0.f, 0.f};

    #pragma unroll
    for (int ks = 0; ks < 4; ++ks) {
        frag_t a[2];
        #pragma unroll
        for (int t = 0; t < 2; ++t) {
            int row = wave * 32 + t * 16 + n16;
            a[t] = *(const frag_t*)&Hs[row * 136 + ks * 32 + quad * 8];
        }
        #pragma unroll
        for (int c = 0; c < 4; ++c) {
            frag_t bf = *(const frag_t*)(W2bf + (c * 16 + n16) * 128 + ks * 32 + quad * 8);
            #pragma unroll
            for (int t = 0; t < 2; ++t)
                acc2[t][c] = __builtin_amdgcn_mfma_f32_16x16x32_bf16(a[t], bf, acc2[t][c], 0, 0, 0);
        }
    }

    // Epilogue: fp32 stores. Per instr: 4 quads x 16 lanes -> 4 x 64B segments.
    float* ob = out + ((long)b * 65280 + eb) * 64;
    #pragma unroll
    for (int c = 0; c < 4; ++c) {
        float bv = b2[c * 16 + n16];
        #pragma unroll
        for (int t = 0; t < 2; ++t) {
            #pragma unroll
            for (int r = 0; r < 4; ++r) {
                int row = wave * 32 + t * 16 + quad * 4 + r;
                ob[row * 64 + c * 16 + n16] = acc2[t][c][r] + bv;
            }
        }
    }
}

extern "C" void kernel_launch(void* const* d_in, const int* in_sizes, int n_in,
                              void* d_out, int out_size, void* d_ws, size_t ws_size,
                              hipStream_t stream) {
    const float* x  = (const float*)d_in[0];
    // d_in[1] = rel_rec, d_in[2] = rel_send: one-hot incidence, replaced by index math
    const float* W1 = (const float*)d_in[3];
    const float* b1 = (const float*)d_in[4];
    const float* W2 = (const float*)d_in[5];
    const float* b2 = (const float*)d_in[6];
    unsigned short* ws = (unsigned short*)d_ws;
    float* out = (float*)d_out;

    cvt_bf16<<<512, 256, 0, stream>>>(x, W1, W2, ws);
    // 8 batches x 510 edge-blocks of 128 edges
    nri_mlp<<<4080, 256, 0, stream>>>(ws, b1, b2, out);
}